// Round 5
// baseline (677.850 us; speedup 1.0000x reference)
//
#include <hip/hip_runtime.h>
#include <hip/hip_bf16.h>
#include <math.h>

// CFConv: out[a][f] = sum_n x[nbr[a][n]][f] * W[a][n][f]
//   W = (softplus(rbf @ w1 + b1)) @ w2 + b2
// N=20000 atoms, NB=32 neighbors, F=128, RBF=64.
//
// R12: switch to mfma_f32_32x32x16_bf16, one atom = all 32 neighbors (M=32).
// Rationale (R11 counters): 96 16x16x32 MFMA/atom each need a 1KB LDS B-frag
// read -> 112 KB LDS/atom ~= 43us of LDS-unit time at 256 CUs; MfmaUtil 12%,
// VALU 31%, HBM 29% -- issue/latency bound on the LDS-fed chain. 32x32x16
// does 2x MACs per fragment: 48 MFMA/atom, ~50 KB LDS/atom, and the H
// staging LDS round-trip disappears entirely:
//  - GEMM1 swapped (C = w1t @ rbft): lane holds col n=lane&31 -- exactly the
//    A-row index GEMM2 needs. The f-quads a lane lacks live in lane^32 only:
//    8 shfl_xor(32) + 8 cndmask blends per slab build GEMM2 A-frags in-reg.
//  - GEMM2 normal: W = H @ (ln2*w2) + b2, acc2 = 4 x f32x16 (64 regs), W in
//    registers through the epilogue (rows = C rows (rr&3)+8*(rr>>2)+4*hi).
//  - LDS = w1t 16KB + w2f 32KB = 48 KB, no band, no fences, one barrier.
//  - 256-thr blocks, __launch_bounds__(256,3): 12 waves/CU for VGPR<=168
//    (peak live ~135; R8/R9 lesson: the 64/64 arch/acc split at (512,4) is
//    what spilled -- avoid tight caps).
//  - rbf prefetch for atom+1 issued right before the epilogue: its 32-reg
//    in-flight window spans only the low-pressure epilogue, latency covered
//    by 64 x-gathers + 64 FMAs.
// Frag layouts (32x32x16): A: row=l&31, k=(l>>5)*8+j. B: col=l&31, same k.
// C/D: col=l&31, row=(reg&3)+8*(reg>>2)+4*(l>>5) [guide-verified].

#define NB     32
#define FD     128
#define RD     64
#define WPB    4      // waves (atoms) per block
#define NTILES 5000   // 20000 / 4

#define LOG2E 1.4426950408889634f
#define LN2   0.6931471805599453f

typedef short  short8  __attribute__((ext_vector_type(8)));
typedef float  floatx4 __attribute__((ext_vector_type(4)));
typedef float  floatx2 __attribute__((ext_vector_type(2)));
typedef float  f32x16  __attribute__((ext_vector_type(16)));

#define NTLOAD(p) __builtin_nontemporal_load((const floatx4*)(p))

static __device__ __forceinline__ unsigned pk2(float a, float b) {
  // packed fp32->bf16 RNE (v_cvt_pk_bf16_f32 on gfx950); low 16 = a
  __hip_bfloat162 h = __float22bfloat162_rn(float2{a, b});
  unsigned u;
  __builtin_memcpy(&u, &h, sizeof(u));
  return u;
}

// log2-domain softplus: log2e folded into GEMM1 operands, ln2 into w2.
static __device__ __forceinline__ float sp2(float acc) {
  return __builtin_amdgcn_logf(1.0f + __builtin_amdgcn_exp2f(acc));
}

__global__ __launch_bounds__(256, 3)  // cap ~168 VGPR -> 12 waves/CU, LDS allows 3 blocks
void cfconv_kernel(const float* __restrict__ x,
                   const float* __restrict__ rbf,
                   const int*   __restrict__ nbr,
                   const float* __restrict__ w1,
                   const float* __restrict__ b1,
                   const float* __restrict__ w2,
                   const float* __restrict__ b2,
                   float* __restrict__ out) {
  // w1t: A-frags of w1^T (GEMM1 swapped). w1t[mt*4+kt][l][j] =
  //   w1[r = kt*16+(l>>5)*8+j][f = mt*32+(l&31)] * log2e
  __shared__ __align__(16) short w1t[16][64][8];   // 16 KB
  // w2f: B-frags of w2. w2f[kt2*4+nt][l][j] =
  //   w2[k = kt2*16+(l>>5)*8+j][n = nt*32+(l&31)] * ln2
  __shared__ __align__(16) short w2f[32][64][8];   // 32 KB  -> 48 KB total

  const int tid  = threadIdx.x;
  const int lane = tid & 63;
  const int wv   = tid >> 6;
  const int c    = lane & 31;   // GEMM1 col n / GEMM2 row n / out f-col
  const int hi   = lane >> 5;   // k-half (A/B) or row-offset (C)

  // ---- prepack weights (with scale folding) -> bf16 frags in LDS ----
  for (int i = tid; i < RD * FD; i += 256) {
    int r = i >> 7, f = i & 127;
    w1t[(f >> 5) * 4 + (r >> 4)][((r >> 3) & 1) * 32 + (f & 31)][r & 7] =
        (short)pk2(w1[i] * LOG2E, 0.f);
  }
  for (int i = tid; i < FD * FD; i += 256) {
    int k = i >> 7, n = i & 127;
    w2f[(k >> 4) * 4 + (n >> 5)][((k >> 3) & 1) * 32 + (n & 31)][k & 7] =
        (short)pk2(w2[i] * LN2, 0.f);
  }
  float b2v[4];
#pragma unroll
  for (int nt = 0; nt < 4; ++nt) b2v[nt] = b2[nt * 32 + c];
  __syncthreads();  // the only barrier; all LDS below is read-only

  // ---- pipeline prologue: rbf loads for the first atom ----
  // lane loads rbf[n=c][r = kt*16 + hi*8 + 0..7] (B = rbf^T frags)
  floatx4 nxt[8];
  {
    const float* s = rbf + (size_t)((blockIdx.x * WPB + wv) * NB + c) * RD + hi * 8;
#pragma unroll
    for (int kt = 0; kt < 4; ++kt) {
      nxt[2 * kt]     = NTLOAD(s + kt * 16);
      nxt[2 * kt + 1] = NTLOAD(s + kt * 16 + 4);
    }
  }

  for (int tile = blockIdx.x; tile < NTILES; tile += gridDim.x) {
    const int atom = tile * WPB + wv;
    const int prow = atom * NB;

    // ---- convert prefetched rbf -> bf16 B-frags ----
    short8 bfr[4];
#pragma unroll
    for (int kt = 0; kt < 4; ++kt) {
      floatx4 lo = nxt[2 * kt], hq = nxt[2 * kt + 1];
      union { short8 s8; unsigned u[4]; } fu;
      fu.u[0] = pk2(lo[0], lo[1]);
      fu.u[1] = pk2(lo[2], lo[3]);
      fu.u[2] = pk2(hq[0], hq[1]);
      fu.u[3] = pk2(hq[2], hq[3]);
      bfr[kt] = fu.s8;
    }

    // ---- GEMM2 accumulators, C-init = b2 (col-indexed -> uniform per lane) ----
    f32x16 acc2[4];
#pragma unroll
    for (int nt = 0; nt < 4; ++nt)
#pragma unroll
      for (int e = 0; e < 16; ++e) acc2[nt][e] = b2v[nt];

    // ---- fused GEMM1-slab -> softplus -> swap -> GEMM2 k-steps ----
#pragma unroll
    for (int mt = 0; mt < 4; ++mt) {
      // b1 row pairs for this slab: rows (2p-pattern) = (p&1)*2+(p>>1)*8 (+4hi)
      floatx2 b1p[8];
#pragma unroll
      for (int p = 0; p < 8; ++p)
        b1p[p] = *(const floatx2*)(b1 + mt * 32 + hi * 4 + (p & 1) * 2 + (p >> 1) * 8);

      // GEMM1: C[f][n] slab, f = mt*32 + rows
      f32x16 acc1 = {};
#pragma unroll
      for (int kt = 0; kt < 4; ++kt) {
        short8 afr = *(const short8*)&w1t[mt * 4 + kt][lane][0];
        acc1 = __builtin_amdgcn_mfma_f32_32x32x16_bf16(afr, bfr[kt], acc1, 0, 0, 0);
      }

      // softplus (log2 domain) + pack pairs of consecutive f rows
      unsigned pw[8], qw[8];
#pragma unroll
      for (int p = 0; p < 8; ++p)
        pw[p] = pk2(sp2(acc1[2 * p] + b1p[p][0]), sp2(acc1[2 * p + 1] + b1p[p][1]));
      // partner lane (lane^32) holds the interleaved f-quads
#pragma unroll
      for (int p = 0; p < 8; ++p)
        qw[p] = (unsigned)__shfl_xor((int)pw[p], 32, 64);

      // assemble GEMM2 A-frags (k = f = (2mt+s)*16 + hi*8 + j) and run k-steps
#pragma unroll
      for (int s = 0; s < 2; ++s) {
        union { short8 s8; unsigned u[4]; } a2;
        a2.u[0] = hi ? qw[4 * s + 2] : pw[4 * s];
        a2.u[1] = hi ? qw[4 * s + 3] : pw[4 * s + 1];
        a2.u[2] = hi ? pw[4 * s + 2] : qw[4 * s];
        a2.u[3] = hi ? pw[4 * s + 3] : qw[4 * s + 1];
#pragma unroll
        for (int nt = 0; nt < 4; ++nt) {
          short8 bf2 = *(const short8*)&w2f[(2 * mt + s) * 4 + nt][lane][0];
          acc2[nt] = __builtin_amdgcn_mfma_f32_32x32x16_bf16(a2.s8, bf2, acc2[nt], 0, 0, 0);
        }
      }
    }

    // ---- issue NEXT atom's rbf loads: in-flight only across the epilogue ----
    {
      int tnext = tile + gridDim.x;
      if (tnext >= NTILES) tnext = tile;  // dummy (valid addr, unused values ok)
      const float* s = rbf + (size_t)((tnext * WPB + wv) * NB + c) * RD + hi * 8;
#pragma unroll
      for (int kt = 0; kt < 4; ++kt) {
        nxt[2 * kt]     = NTLOAD(s + kt * 16);
        nxt[2 * kt + 1] = NTLOAD(s + kt * 16 + 4);
      }
    }

    // ---- epilogue: lane owns f = nt*32 + c; rows rr -> neighbor n(rr,hi) ----
    const int* nbp = nbr + prow;
    float o[4] = {0.f, 0.f, 0.f, 0.f};
#pragma unroll
    for (int rr = 0; rr < 16; ++rr) {
      const int row = (rr & 3) + 8 * (rr >> 2) + 4 * hi;
      const int j   = nbp[row];                      // 2 addrs per wave, L1-hot
      const float* xp = x + (size_t)j * FD + c;      // 2x128B coalesced per load
      float xv0 = xp[0], xv1 = xp[32], xv2 = xp[64], xv3 = xp[96];
      o[0] = fmaf(xv0, acc2[0][rr], o[0]);
      o[1] = fmaf(xv1, acc2[1][rr], o[1]);
      o[2] = fmaf(xv2, acc2[2][rr], o[2]);
      o[3] = fmaf(xv3, acc2[3][rr], o[3]);
    }
    // partner lane has the complementary 16 neighbors of the same f columns
#pragma unroll
    for (int nt = 0; nt < 4; ++nt) o[nt] += __shfl_xor(o[nt], 32, 64);

    // hi=0 stores f = c, 32+c ; hi=1 stores f = 64+c, 96+c (no divergence)
    float s0 = hi ? o[2] : o[0];
    float s1 = hi ? o[3] : o[1];
    float* op = out + (size_t)atom * FD + hi * 64 + c;
    __builtin_nontemporal_store(s0, op);
    __builtin_nontemporal_store(s1, op + 32);
  }
}

extern "C" void kernel_launch(void* const* d_in, const int* in_sizes, int n_in,
                              void* d_out, int out_size, void* d_ws, size_t ws_size,
                              hipStream_t stream) {
  const float* x   = (const float*)d_in[0];
  const float* rbf = (const float*)d_in[1];
  const int*   nbr = (const int*)d_in[2];
  const float* w1  = (const float*)d_in[3];
  const float* b1  = (const float*)d_in[4];
  const float* w2  = (const float*)d_in[5];
  const float* b2  = (const float*)d_in[6];
  float* out = (float*)d_out;

  // 48 KB LDS, 256-thr blocks -> 3 blocks/CU (12 waves/CU at <=168 VGPR).
  // 1250 blocks x 4 tiles each: exact cover of 5000 atom-groups.
  cfconv_kernel<<<dim3(1250), dim3(256), 0, stream>>>(x, rbf, nbr, w1, b1, w2, b2, out);
}

// Round 6
// 605.155 us; speedup vs baseline: 1.1201x; 1.1201x over previous
//
#include <hip/hip_runtime.h>
#include <hip/hip_bf16.h>
#include <math.h>

// CFConv: out[a][f] = sum_n x[nbr[a][n]][f] * W[a][n][f]
//   W = (softplus(rbf @ w1 + b1)) @ w2 + b2
// N=20000 atoms, NB=32 neighbors, F=128, RBF=64.
//
// R13 = R12's 32x32x16 structure (numerically VERIFIED in R12: passed with
// absmax 0.25 despite the spill) with the register schedule fixed. R12 spilled
// 372MB/dispatch (dispatch 527us was literally spill-BW-bound) because
// acc2(64) + bfr(16) + acc1(16) + pw/qw(16) + b1p(16) + nxt(32) were all live
// inside the fused mt loop under a ~170-reg cap. R13 restructures:
//  - mt loop ONLY builds the 8 GEMM2 A-frags hA[8] (32 regs; pw/qw/acc1 die
//    per slab). acc2 is NOT live during GEMM1. Peak ~115 regs.
//  - GEMM2 split into 2 passes of 2 n-tiles (acc2 = 32 regs each), each pass
//    consumed immediately by its epilogue half (cols 0-63, then 64-127).
//  - rbf prefetch for atom+1 issued after pass-1 GEMM2: its 32-reg window
//    spans only {pass1 epilogue + pass2} (~75 regs live), ~1500cy cover.
//  - 512-thr blocks (8 waves share the 48KB weight prepack), grid 500,
//    __launch_bounds__(512,2) -- avoids the (512,4) 64/64 split trap.
// Per-atom cost vs R11: LDS 119KB -> 48KB, MFMA 96 -> 48, H LDS round-trip
// and all LDS fences GONE (H reassembled in-register via shfl_xor(32)).
// Frag layouts (32x32x16, R12-verified): A: row=l&31, k=(l>>5)*8+j. B: same.
// C/D: col=l&31, row=(reg&3)+8*(reg>>2)+4*(l>>5).

#define NB     32
#define FD     128
#define RD     64
#define WPB    8      // waves (atoms) per block
#define NTILES 2500   // 20000 / 8

#define LOG2E 1.4426950408889634f
#define LN2   0.6931471805599453f

typedef short  short8  __attribute__((ext_vector_type(8)));
typedef float  floatx4 __attribute__((ext_vector_type(4)));
typedef float  floatx2 __attribute__((ext_vector_type(2)));
typedef float  f32x16  __attribute__((ext_vector_type(16)));

#define NTLOAD(p) __builtin_nontemporal_load((const floatx4*)(p))

static __device__ __forceinline__ unsigned pk2(float a, float b) {
  // packed fp32->bf16 RNE (v_cvt_pk_bf16_f32 on gfx950); low 16 = a
  __hip_bfloat162 h = __float22bfloat162_rn(float2{a, b});
  unsigned u;
  __builtin_memcpy(&u, &h, sizeof(u));
  return u;
}

// log2-domain softplus: log2e folded into GEMM1 operands, ln2 into w2.
static __device__ __forceinline__ float sp2(float acc) {
  return __builtin_amdgcn_logf(1.0f + __builtin_amdgcn_exp2f(acc));
}

__global__ __launch_bounds__(512, 2)  // 256-reg cap; target allocation ~120
void cfconv_kernel(const float* __restrict__ x,
                   const float* __restrict__ rbf,
                   const int*   __restrict__ nbr,
                   const float* __restrict__ w1,
                   const float* __restrict__ b1,
                   const float* __restrict__ w2,
                   const float* __restrict__ b2,
                   float* __restrict__ out) {
  // w1t: A-frags of w1^T (GEMM1 swapped). w1t[mt*4+kt][l][j] =
  //   w1[r = kt*16+(l>>5)*8+j][f = mt*32+(l&31)] * log2e
  __shared__ __align__(16) short w1t[16][64][8];   // 16 KB
  // w2f: B-frags of w2. w2f[kt2*4+nt][l][j] =
  //   w2[k = kt2*16+(l>>5)*8+j][n = nt*32+(l&31)] * ln2
  __shared__ __align__(16) short w2f[32][64][8];   // 32 KB  -> 48 KB total

  const int tid  = threadIdx.x;
  const int lane = tid & 63;
  const int wv   = tid >> 6;
  const int c    = lane & 31;   // GEMM1 col n / GEMM2 row n / out f-col
  const int hi   = lane >> 5;   // k-half (A/B) or row-offset (C)

  // ---- prepack weights (with scale folding) -> bf16 frags in LDS ----
  for (int i = tid; i < RD * FD; i += 512) {
    int r = i >> 7, f = i & 127;
    w1t[(f >> 5) * 4 + (r >> 4)][((r >> 3) & 1) * 32 + (f & 31)][r & 7] =
        (short)pk2(w1[i] * LOG2E, 0.f);
  }
  for (int i = tid; i < FD * FD; i += 512) {
    int k = i >> 7, n = i & 127;
    w2f[(k >> 4) * 4 + (n >> 5)][((k >> 3) & 1) * 32 + (n & 31)][k & 7] =
        (short)pk2(w2[i] * LN2, 0.f);
  }
  float b2v[4];
#pragma unroll
  for (int nt = 0; nt < 4; ++nt) b2v[nt] = b2[nt * 32 + c];
  __syncthreads();  // the only barrier; all LDS below is read-only

  // ---- pipeline prologue: rbf loads for the first atom ----
  // lane loads rbf[n=c][r = kt*16 + hi*8 + 0..7] (B = rbf^T frags)
  floatx4 nxt[8];
  {
    const float* s = rbf + (size_t)((blockIdx.x * WPB + wv) * NB + c) * RD + hi * 8;
#pragma unroll
    for (int kt = 0; kt < 4; ++kt) {
      nxt[2 * kt]     = NTLOAD(s + kt * 16);
      nxt[2 * kt + 1] = NTLOAD(s + kt * 16 + 4);
    }
  }

  for (int tile = blockIdx.x; tile < NTILES; tile += gridDim.x) {
    const int atom = tile * WPB + wv;
    const int* nbp = nbr + (size_t)atom * NB;

    // ---- convert prefetched rbf -> bf16 B-frags (nxt dies here) ----
    short8 bfr[4];
#pragma unroll
    for (int kt = 0; kt < 4; ++kt) {
      floatx4 lo = nxt[2 * kt], hq = nxt[2 * kt + 1];
      union { short8 s8; unsigned u[4]; } fu;
      fu.u[0] = pk2(lo[0], lo[1]);
      fu.u[1] = pk2(lo[2], lo[3]);
      fu.u[2] = pk2(hq[0], hq[1]);
      fu.u[3] = pk2(hq[2], hq[3]);
      bfr[kt] = fu.s8;
    }

    // ---- GEMM1 slabs -> softplus -> shfl -> hA[8] (GEMM2 A-frags) ----
    // acc2 NOT live here; per slab only acc1(16)+pw(8)+qw(8) transient.
    short8 hA[8];
#pragma unroll
    for (int mt = 0; mt < 4; ++mt) {
      // GEMM1: C[f][n] slab, f = mt*32 + ((reg&3)+8*(reg>>2)+4*hi)
      f32x16 acc1 = {};
#pragma unroll
      for (int kt = 0; kt < 4; ++kt) {
        short8 afr = *(const short8*)&w1t[mt * 4 + kt][lane][0];
        acc1 = __builtin_amdgcn_mfma_f32_32x32x16_bf16(afr, bfr[kt], acc1, 0, 0, 0);
      }

      // softplus (log2 domain) on consecutive-f row pairs + pack to bf16
      unsigned pw[8], qw[8];
#pragma unroll
      for (int p = 0; p < 8; ++p) {
        floatx2 b1p = *(const floatx2*)(b1 + mt * 32 + hi * 4 + (p & 1) * 2 + (p >> 1) * 8);
        pw[p] = pk2(sp2(acc1[2 * p] + b1p[0]), sp2(acc1[2 * p + 1] + b1p[1]));
      }
      // partner lane (lane^32) holds the interleaved f-quads
#pragma unroll
      for (int p = 0; p < 8; ++p)
        qw[p] = (unsigned)__shfl_xor((int)pw[p], 32, 64);

      // assemble GEMM2 A-frags: hA[2mt+s] covers k = (2mt+s)*16 + hi*8 + j
#pragma unroll
      for (int s = 0; s < 2; ++s) {
        union { short8 s8; unsigned u[4]; } a2;
        a2.u[0] = hi ? qw[4 * s + 2] : pw[4 * s];
        a2.u[1] = hi ? qw[4 * s + 3] : pw[4 * s + 1];
        a2.u[2] = hi ? pw[4 * s + 2] : qw[4 * s];
        a2.u[3] = hi ? pw[4 * s + 3] : qw[4 * s + 1];
        hA[2 * mt + s] = a2.s8;
      }
    }

    // ---- GEMM2 pass 1: n-tiles 0,1 (acc2 = 32 regs; hA stays live) ----
    f32x16 acc2[2];
#pragma unroll
    for (int u = 0; u < 2; ++u)
#pragma unroll
      for (int e = 0; e < 16; ++e) acc2[u][e] = b2v[u];
#pragma unroll
    for (int kt2 = 0; kt2 < 8; ++kt2)
#pragma unroll
      for (int u = 0; u < 2; ++u) {
        short8 bf2 = *(const short8*)&w2f[kt2 * 4 + u][lane][0];
        acc2[u] = __builtin_amdgcn_mfma_f32_32x32x16_bf16(hA[kt2], bf2, acc2[u], 0, 0, 0);
      }

    // ---- issue NEXT atom's rbf loads: window spans pass1-epilogue + pass2 ----
    {
      int tnext = tile + gridDim.x;
      if (tnext >= NTILES) tnext = tile;  // dummy (valid addr, values unused)
      const float* s = rbf + (size_t)((tnext * WPB + wv) * NB + c) * RD + hi * 8;
#pragma unroll
      for (int kt = 0; kt < 4; ++kt) {
        nxt[2 * kt]     = NTLOAD(s + kt * 16);
        nxt[2 * kt + 1] = NTLOAD(s + kt * 16 + 4);
      }
    }

    // ---- epilogue pass 1: f-cols c, 32+c; rows rr -> neighbor n(rr,hi) ----
    float o0 = 0.f, o1 = 0.f, o2 = 0.f, o3 = 0.f;
#pragma unroll
    for (int rr = 0; rr < 16; ++rr) {
      const int row = (rr & 3) + 8 * (rr >> 2) + 4 * hi;
      const int j   = nbp[row];                      // 2 addrs/wave, L1-hot
      const float* xp = x + (size_t)j * FD + c;      // 128B coalesced per half-wave
      o0 = fmaf(xp[0],  acc2[0][rr], o0);
      o1 = fmaf(xp[32], acc2[1][rr], o1);
    }

    // ---- GEMM2 pass 2: n-tiles 2,3 (hA dies here) ----
#pragma unroll
    for (int u = 0; u < 2; ++u)
#pragma unroll
      for (int e = 0; e < 16; ++e) acc2[u][e] = b2v[2 + u];
#pragma unroll
    for (int kt2 = 0; kt2 < 8; ++kt2)
#pragma unroll
      for (int u = 0; u < 2; ++u) {
        short8 bf2 = *(const short8*)&w2f[kt2 * 4 + 2 + u][lane][0];
        acc2[u] = __builtin_amdgcn_mfma_f32_32x32x16_bf16(hA[kt2], bf2, acc2[u], 0, 0, 0);
      }

    // ---- epilogue pass 2: f-cols 64+c, 96+c ----
#pragma unroll
    for (int rr = 0; rr < 16; ++rr) {
      const int row = (rr & 3) + 8 * (rr >> 2) + 4 * hi;
      const int j   = nbp[row];                      // L1-hot reload
      const float* xp = x + (size_t)j * FD + c;
      o2 = fmaf(xp[64], acc2[0][rr], o2);
      o3 = fmaf(xp[96], acc2[1][rr], o3);
    }

    // ---- partner lane holds the complementary 16 neighbors; reduce + store ----
    o0 += __shfl_xor(o0, 32, 64);
    o1 += __shfl_xor(o1, 32, 64);
    o2 += __shfl_xor(o2, 32, 64);
    o3 += __shfl_xor(o3, 32, 64);

    // hi=0 stores f = c, 32+c ; hi=1 stores f = 64+c, 96+c (no divergence)
    float s0 = hi ? o2 : o0;
    float s1 = hi ? o3 : o1;
    float* op = out + (size_t)atom * FD + hi * 64 + c;
    __builtin_nontemporal_store(s0, op);
    __builtin_nontemporal_store(s1, op + 32);
  }
}

extern "C" void kernel_launch(void* const* d_in, const int* in_sizes, int n_in,
                              void* d_out, int out_size, void* d_ws, size_t ws_size,
                              hipStream_t stream) {
  const float* x   = (const float*)d_in[0];
  const float* rbf = (const float*)d_in[1];
  const int*   nbr = (const int*)d_in[2];
  const float* w1  = (const float*)d_in[3];
  const float* b1  = (const float*)d_in[4];
  const float* w2  = (const float*)d_in[5];
  const float* b2  = (const float*)d_in[6];
  float* out = (float*)d_out;

  // 48 KB LDS, 512-thr blocks -> 2 blocks/CU at VGPR<=128.
  // 500 blocks x 5 tiles each, grid-stride over 2500 atom-groups of 8.
  cfconv_kernel<<<dim3(500), dim3(512), 0, stream>>>(x, rbf, nbr, w1, b1, w2, b2, out);
}

// Round 7
// 345.414 us; speedup vs baseline: 1.9624x; 1.7520x over previous
//
#include <hip/hip_runtime.h>
#include <hip/hip_bf16.h>
#include <math.h>

// CFConv: out[a][f] = sum_n x[nbr[a][n]][f] * W[a][n][f]
//   W = (softplus(rbf @ w1 + b1)) @ w2 + b2
// N=20000 atoms, NB=32 neighbors, F=128, RBF=64.
//
// R14 = R12/R13's 32x32x16 compute (numerically verified twice) with the
// epilogue changed to R7-style W-via-LDS consumption. R13 still spilled
// (WRITE 222MB, VGPR pinned 128, 428us): lesson -- the backend gives the
// arch side at most ~128 VGPRs when MFMA accs are present; any epilogue
// that consumes W from registers doesn't fit. R7 (95us, zero spill) worked
// because accumulators died into LDS right after each GEMM. So:
//  - GEMM1 swapped (C = w1t @ rbft) + shfl_xor(32) H-reassembly -> hA[8]
//    (verbatim R13, verified).
//  - GEMM2 in 2 passes of 2 n-tiles; after each pass acc2 is pk2-packed to a
//    4KB wave-private LDS band [32 rows][32 c] u32 (16 ds_write_b32, 2-way
//    conflict = free) and DIES. Epilogue per neighbor-row: wave-uniform
//    s_load j, 2 coalesced x dwords/lane, 1 broadcast ds_read_b32, 2 FMA.
//    Each lane accumulates 2 f-columns per pass; NO shuffles, ~10 live regs.
//    All 32 x rows (16KB) are L1-resident for pass 2's reload.
//  - Band reused across passes (wave-private, compiler fences only).
//  - rbf prefetch for atom+1 issued before epilogue pass 1 (window = epi1 +
//    GEMM2 pass 2 + epi2, arch-cheap phases).
// LDS/atom ~72KB (vs R11 119KB), MFMA 48 (vs 96), LDS total 80KB ->
// 2 blocks/CU, 16 waves/CU.
// Frag layouts (32x32x16, R12/R13-verified): A: row=l&31, k=(l>>5)*8+j.
// B: col=l&31, same k. C/D: col=l&31, row=(reg&3)+8*(reg>>2)+4*(l>>5).

#define NB     32
#define FD     128
#define RD     64
#define WAVES  8      // waves (atoms) per block
#define NTILES 2500   // 20000 / 8

#define LOG2E 1.4426950408889634f
#define LN2   0.6931471805599453f

typedef short  short8  __attribute__((ext_vector_type(8)));
typedef float  floatx4 __attribute__((ext_vector_type(4)));
typedef float  floatx2 __attribute__((ext_vector_type(2)));
typedef float  f32x16  __attribute__((ext_vector_type(16)));

#define LDS_FENCE() asm volatile("" ::: "memory")  // compiler-only ordering
#define NTLOAD(p) __builtin_nontemporal_load((const floatx4*)(p))

static __device__ __forceinline__ unsigned pk2(float a, float b) {
  // packed fp32->bf16 RNE (v_cvt_pk_bf16_f32 on gfx950); low 16 = a
  __hip_bfloat162 h = __float22bfloat162_rn(float2{a, b});
  unsigned u;
  __builtin_memcpy(&u, &h, sizeof(u));
  return u;
}

// log2-domain softplus: log2e folded into GEMM1 operands, ln2 into w2.
static __device__ __forceinline__ float sp2(float acc) {
  return __builtin_amdgcn_logf(1.0f + __builtin_amdgcn_exp2f(acc));
}

__global__ __launch_bounds__(512, 2)
void cfconv_kernel(const float* __restrict__ x,
                   const float* __restrict__ rbf,
                   const int*   __restrict__ nbr,
                   const float* __restrict__ w1,
                   const float* __restrict__ b1,
                   const float* __restrict__ w2,
                   const float* __restrict__ b2,
                   float* __restrict__ out) {
  // w1t: A-frags of w1^T (GEMM1 swapped). w1t[mt*4+kt][l][j] =
  //   w1[r = kt*16+(l>>5)*8+j][f = mt*32+(l&31)] * log2e
  __shared__ __align__(16) short w1t[16][64][8];   // 16 KB
  // w2f: B-frags of w2. w2f[kt2*4+nt][l][j] =
  //   w2[k = kt2*16+(l>>5)*8+j][n = nt*32+(l&31)] * ln2
  __shared__ __align__(16) short w2f[32][64][8];   // 32 KB
  // per-wave W band: row = neighbor n, col c; u32 = pk2(W[n][fA], W[n][fB])
  __shared__ __align__(16) unsigned wband[WAVES][32][32];  // 32 KB -> 80 KB total

  const int tid  = threadIdx.x;
  const int lane = tid & 63;
  const int wv   = tid >> 6;
  const int c    = lane & 31;   // GEMM1 col n / GEMM2 f-col / band col
  const int hi   = lane >> 5;   // k-half (A/B) or row-offset (C)

  // ---- prepack weights (with scale folding) -> bf16 frags in LDS ----
  for (int i = tid; i < RD * FD; i += 512) {
    int r = i >> 7, f = i & 127;
    w1t[(f >> 5) * 4 + (r >> 4)][((r >> 3) & 1) * 32 + (f & 31)][r & 7] =
        (short)pk2(w1[i] * LOG2E, 0.f);
  }
  for (int i = tid; i < FD * FD; i += 512) {
    int k = i >> 7, n = i & 127;
    w2f[(k >> 4) * 4 + (n >> 5)][((k >> 3) & 1) * 32 + (n & 31)][k & 7] =
        (short)pk2(w2[i] * LN2, 0.f);
  }
  float b2v[4];
#pragma unroll
  for (int nt = 0; nt < 4; ++nt) b2v[nt] = b2[nt * 32 + c];
  __syncthreads();  // the only barrier; wband use below is wave-private

  unsigned (*band)[32] = wband[wv];

  // ---- pipeline prologue: rbf loads for the first atom ----
  // lane loads rbf[n=c][r = kt*16 + hi*8 + 0..7] (B = rbf^T frags)
  floatx4 nxt[8];
  {
    const float* s = rbf + (size_t)((blockIdx.x * WAVES + wv) * NB + c) * RD + hi * 8;
#pragma unroll
    for (int kt = 0; kt < 4; ++kt) {
      nxt[2 * kt]     = NTLOAD(s + kt * 16);
      nxt[2 * kt + 1] = NTLOAD(s + kt * 16 + 4);
    }
  }

  for (int tile = blockIdx.x; tile < NTILES; tile += gridDim.x) {
    const int atom = tile * WAVES + wv;
    const int* nbp = nbr + (size_t)atom * NB;

    // ---- convert prefetched rbf -> bf16 B-frags (nxt dies here) ----
    short8 bfr[4];
#pragma unroll
    for (int kt = 0; kt < 4; ++kt) {
      floatx4 lo = nxt[2 * kt], hq = nxt[2 * kt + 1];
      union { short8 s8; unsigned u[4]; } fu;
      fu.u[0] = pk2(lo[0], lo[1]);
      fu.u[1] = pk2(lo[2], lo[3]);
      fu.u[2] = pk2(hq[0], hq[1]);
      fu.u[3] = pk2(hq[2], hq[3]);
      bfr[kt] = fu.s8;
    }

    // ---- GEMM1 slabs -> softplus -> shfl -> hA[8] (verbatim R13, verified) ----
    short8 hA[8];
#pragma unroll
    for (int mt = 0; mt < 4; ++mt) {
      // GEMM1: C[f][n] slab, f = mt*32 + ((reg&3)+8*(reg>>2)+4*hi)
      f32x16 acc1 = {};
#pragma unroll
      for (int kt = 0; kt < 4; ++kt) {
        short8 afr = *(const short8*)&w1t[mt * 4 + kt][lane][0];
        acc1 = __builtin_amdgcn_mfma_f32_32x32x16_bf16(afr, bfr[kt], acc1, 0, 0, 0);
      }

      // softplus (log2 domain) on consecutive-f row pairs + pack to bf16
      unsigned pw[8], qw[8];
#pragma unroll
      for (int p = 0; p < 8; ++p) {
        floatx2 b1p = *(const floatx2*)(b1 + mt * 32 + hi * 4 + (p & 1) * 2 + (p >> 1) * 8);
        pw[p] = pk2(sp2(acc1[2 * p] + b1p[0]), sp2(acc1[2 * p + 1] + b1p[1]));
      }
      // partner lane (lane^32) holds the interleaved f-quads
#pragma unroll
      for (int p = 0; p < 8; ++p)
        qw[p] = (unsigned)__shfl_xor((int)pw[p], 32, 64);

      // assemble GEMM2 A-frags: hA[2mt+s] covers k = (2mt+s)*16 + hi*8 + j
#pragma unroll
      for (int s = 0; s < 2; ++s) {
        union { short8 s8; unsigned u[4]; } a2;
        a2.u[0] = hi ? qw[4 * s + 2] : pw[4 * s];
        a2.u[1] = hi ? qw[4 * s + 3] : pw[4 * s + 1];
        a2.u[2] = hi ? pw[4 * s + 2] : qw[4 * s];
        a2.u[3] = hi ? pw[4 * s + 3] : qw[4 * s + 1];
        hA[2 * mt + s] = a2.s8;
      }
    }

    float o0 = 0.f, o1 = 0.f, o2 = 0.f, o3 = 0.f;

    { // ---- GEMM2 pass 1: n-tiles 0,1 (f = c and 32+c) ----
      f32x16 acc2[2];
#pragma unroll
      for (int u = 0; u < 2; ++u)
#pragma unroll
        for (int e = 0; e < 16; ++e) acc2[u][e] = b2v[u];
#pragma unroll
      for (int kt2 = 0; kt2 < 8; ++kt2)
#pragma unroll
        for (int u = 0; u < 2; ++u) {
          short8 bf2 = *(const short8*)&w2f[kt2 * 4 + u][lane][0];
          acc2[u] = __builtin_amdgcn_mfma_f32_32x32x16_bf16(hA[kt2], bf2, acc2[u], 0, 0, 0);
        }
      // dump W pass 1 into band: row = C row, u32 = (f=c | f=32+c)
#pragma unroll
      for (int rr = 0; rr < 16; ++rr) {
        const int row = (rr & 3) + 8 * (rr >> 2) + 4 * hi;
        band[row][c] = pk2(acc2[0][rr], acc2[1][rr]);
      }
    }
    LDS_FENCE();  // band writes precede epilogue-1 reads

    // ---- issue NEXT atom's rbf loads (window: epi1 + GEMM2 p2 + epi2) ----
    {
      int tnext = tile + gridDim.x;
      if (tnext >= NTILES) tnext = tile;  // dummy (valid addr, values unused)
      const float* s = rbf + (size_t)((tnext * WAVES + wv) * NB + c) * RD + hi * 8;
#pragma unroll
      for (int kt = 0; kt < 4; ++kt) {
        nxt[2 * kt]     = NTLOAD(s + kt * 16);
        nxt[2 * kt + 1] = NTLOAD(s + kt * 16 + 4);
      }
    }

    // ---- epilogue pass 1: f-cols c, 32+c over all 32 neighbor rows ----
#pragma unroll 8
    for (int n = 0; n < 32; ++n) {
      const int j = nbp[n];                       // wave-uniform -> s_load
      const float* xp = x + (size_t)j * FD;       // 512B row, L1-resident later
      const unsigned u = band[n][c];              // broadcast read, conflict-free
      o0 = fmaf(xp[c],      __builtin_bit_cast(float, u << 16),          o0);
      o1 = fmaf(xp[c + 32], __builtin_bit_cast(float, u & 0xFFFF0000u),  o1);
    }
    LDS_FENCE();  // epilogue-1 reads precede pass-2 band overwrite

    { // ---- GEMM2 pass 2: n-tiles 2,3 (f = 64+c and 96+c); hA dies here ----
      f32x16 acc2[2];
#pragma unroll
      for (int u = 0; u < 2; ++u)
#pragma unroll
        for (int e = 0; e < 16; ++e) acc2[u][e] = b2v[2 + u];
#pragma unroll
      for (int kt2 = 0; kt2 < 8; ++kt2)
#pragma unroll
        for (int u = 0; u < 2; ++u) {
          short8 bf2 = *(const short8*)&w2f[kt2 * 4 + 2 + u][lane][0];
          acc2[u] = __builtin_amdgcn_mfma_f32_32x32x16_bf16(hA[kt2], bf2, acc2[u], 0, 0, 0);
        }
#pragma unroll
      for (int rr = 0; rr < 16; ++rr) {
        const int row = (rr & 3) + 8 * (rr >> 2) + 4 * hi;
        band[row][c] = pk2(acc2[0][rr], acc2[1][rr]);
      }
    }
    LDS_FENCE();  // pass-2 writes precede epilogue-2 reads

    // ---- epilogue pass 2: f-cols 64+c, 96+c (x rows L1-hot) ----
#pragma unroll 8
    for (int n = 0; n < 32; ++n) {
      const int j = nbp[n];
      const float* xp = x + (size_t)j * FD;
      const unsigned u = band[n][c];
      o2 = fmaf(xp[c + 64], __builtin_bit_cast(float, u << 16),          o2);
      o3 = fmaf(xp[c + 96], __builtin_bit_cast(float, u & 0xFFFF0000u),  o3);
    }
    LDS_FENCE();  // epilogue-2 reads precede next tile's band writes

    // ---- store: hi=0 -> f = c, 32+c ; hi=1 -> f = 64+c, 96+c ----
    float s0 = hi ? o2 : o0;
    float s1 = hi ? o3 : o1;
    float* op = out + (size_t)atom * FD + hi * 64 + c;
    __builtin_nontemporal_store(s0, op);
    __builtin_nontemporal_store(s1, op + 32);
  }
}

extern "C" void kernel_launch(void* const* d_in, const int* in_sizes, int n_in,
                              void* d_out, int out_size, void* d_ws, size_t ws_size,
                              hipStream_t stream) {
  const float* x   = (const float*)d_in[0];
  const float* rbf = (const float*)d_in[1];
  const int*   nbr = (const int*)d_in[2];
  const float* w1  = (const float*)d_in[3];
  const float* b1  = (const float*)d_in[4];
  const float* w2  = (const float*)d_in[5];
  const float* b2  = (const float*)d_in[6];
  float* out = (float*)d_out;

  // 80 KB LDS -> 2 blocks/CU (16 waves/CU). 500 blocks x 5 tiles, grid-stride.
  cfconv_kernel<<<dim3(500), dim3(512), 0, stream>>>(x, rbf, nbr, w1, b1, w2, b2, out);
}

// Round 8
// 320.108 us; speedup vs baseline: 2.1176x; 1.0791x over previous
//
#include <hip/hip_runtime.h>
#include <hip/hip_bf16.h>
#include <math.h>

// CFConv: out[a][f] = sum_n x[nbr[a][n]][f] * W[a][n][f]
//   W = (softplus(rbf @ w1 + b1)) @ w2 + b2
// N=20000 atoms, NB=32 neighbors, F=128, RBF=64.
//
// R15 = R7 (the session champion, ~95us dispatch, zero spill, all-LDS
// dataflow) + ONE lever: cross-half rbf prefetch, under (512,2).
// Rounds 8-14 post-mortem: every register-resident-W design spilled or lost
// ILP. R14 (32x32, no-spill) landed at 152us -- worse than R7 -- because
// 32x32 trades 8 independent short MFMA chains for 1-2 long serial ones,
// serializes softplus behind 32 ds_bpermute, and quadruples epilogue VMEM
// instruction count. Abandoned. R7's structure stands; its one measured
// exposed latency is the 4 rbf b128 loads issued cold each half (~900cy HBM,
// zero cover). R11 proved the prefetch lever on this exact load pattern
// (130 -> 108us). Changes vs R7:
//  - pre[4] floatx4 double-buffer: prologue loads (tile0, half0); each half
//    converts pre -> afrag then immediately issues the NEXT half's 4 loads
//    (cover = GEMM1 + softplus + GEMM2 + epilogue instead of 0).
//  - __launch_bounds__(512,2): +16 live regs breaks the (512,4) 64-arch
//    partition (R8/R9 lesson); (512,2) gives ~104 regs with no spill (R10
//    precedent) and keeps 4 waves/SIMD while VGPR <= 128.
// Everything else is R7 verbatim: 80 KB LDS (2 blocks/CU, 16 waves/CU),
// 8 waves/block, one atom per wave in two 16-row halves; swizzled
// wave-private LDS band stages H then W; scale-folded log2-domain softplus
// (w1,b1 pre-scaled by log2e, w2 by ln2); epilogue does coalesced 512B
// x-row reads in-loop (lane owns f=2*lane, 2*lane+1); LDS_FENCE ordering.

#define NB     32
#define FD     128
#define RD     64
#define WAVES  8
#define NTILES 2500   // 20000 / 8

#define LOG2E 1.4426950408889634f
#define LN2   0.6931471805599453f

typedef short  short8  __attribute__((ext_vector_type(8)));
typedef float  floatx4 __attribute__((ext_vector_type(4)));
typedef float  floatx2 __attribute__((ext_vector_type(2)));

#define LDS_FENCE() asm volatile("" ::: "memory")  // compiler-only ordering, no instr
#define NTLOAD(p) __builtin_nontemporal_load((const floatx4*)(p))

static __device__ __forceinline__ unsigned pk2(float a, float b) {
  // packed fp32->bf16 RNE (v_cvt_pk_bf16_f32 on gfx950); low 16 = a
  __hip_bfloat162 h = __float22bfloat162_rn(float2{a, b});
  unsigned u;
  __builtin_memcpy(&u, &h, sizeof(u));
  return u;
}

// log2-domain softplus: log2e folded into GEMM1 operands, ln2 into w2.
static __device__ __forceinline__ float sp2(float acc) {
  return __builtin_amdgcn_logf(1.0f + __builtin_amdgcn_exp2f(acc));
}

__global__ __launch_bounds__(512, 2)  // ~104-reg allocation, no spill (R10), 4 w/SIMD while <=128
void cfconv_kernel(const float* __restrict__ x,
                   const float* __restrict__ rbf,
                   const int*   __restrict__ nbr,
                   const float* __restrict__ w1,
                   const float* __restrict__ b1,
                   const float* __restrict__ w2,
                   const float* __restrict__ b2,
                   float* __restrict__ out) {
  // B-fragment layout: frag[kt*8+nt][lane][j] = B[kt*32 + (lane>>4)*8 + j][nt*16 + (lane&15)]
  __shared__ __align__(16) short w1f[16][64][8];        // 16 KB
  __shared__ __align__(16) short w2f[32][64][8];        // 32 KB
  // per-wave 16-row x 128-col bf16 staging (H, then W); 16B-block XOR swizzle:
  // element (row, col) lives at band[row][ ((col>>3 ^ row)&15)*8 + (col&7) ]
  __shared__ __align__(16) short hbuf[WAVES * 16][128]; // 32 KB -> total exactly 80 KB

  const int tid  = threadIdx.x;
  const int lane = tid & 63;
  const int wv   = tid >> 6;
  const int q    = lane >> 4;   // k-quad (A/B) or row-quad (C)
  const int ln   = lane & 15;   // m (A/C row) or n (B/C col) inside a 16-tile

  // ---- prepack weights (with scale folding) -> bf16 B-frags in LDS ----
  for (int i = tid; i < RD * FD; i += 512) {
    int k = i >> 7, n = i & 127, kk = k & 31;
    w1f[(k >> 5) * 8 + (n >> 4)][(kk >> 3) * 16 + (n & 15)][kk & 7] =
        (short)pk2(w1[i] * LOG2E, 0.f);
  }
  for (int i = tid; i < FD * FD; i += 512) {
    int k = i >> 7, n = i & 127, kk = k & 31;
    w2f[(k >> 5) * 8 + (n >> 4)][(kk >> 3) * 16 + (n & 15)][kk & 7] =
        (short)pk2(w2[i] * LN2, 0.f);
  }
  float b1v[8], b2v[8];
#pragma unroll
  for (int nt = 0; nt < 8; ++nt) {
    b1v[nt] = b1[nt * 16 + ln] * LOG2E;
    b2v[nt] = b2[nt * 16 + ln];
  }
  __syncthreads();  // the only barrier; hbuf use below is wave-private

  short (*band)[128] = &hbuf[wv * 16];
  const int cb2 = (lane * 2) >> 3;   // epilogue col-block for f = {2*lane, 2*lane+1}
  const int cl2 = (lane * 2) & 7;

  // ---- pipeline prologue: rbf loads for (first tile, half 0) ----
  floatx4 pre[4];
  {
    const float* s = rbf + (size_t)((blockIdx.x * WAVES + wv) * NB + ln) * RD + q * 8;
    pre[0] = NTLOAD(s);      pre[1] = NTLOAD(s + 4);
    pre[2] = NTLOAD(s + 32); pre[3] = NTLOAD(s + 36);
  }

  for (int tile = blockIdx.x; tile < NTILES; tile += gridDim.x) {
    const int atom = tile * WAVES + wv;
    const int prow = atom * NB;
    const int* nbp = nbr + prow;
    int tnext = tile + gridDim.x;
    if (tnext >= NTILES) tnext = tile;            // dummy (valid addr, unused)
    const int prow_nxt = (tnext * WAVES + wv) * NB;

    float o0 = 0.f, o1 = 0.f;

#pragma unroll
    for (int mt = 0; mt < 2; ++mt) {
      // ---- convert prefetched rbf -> A-frags (pre dies here) ----
      short8 afrag[2];
#pragma unroll
      for (int kt = 0; kt < 2; ++kt) {
        floatx4 lo = pre[kt * 2], hi = pre[kt * 2 + 1];
        union { short8 s8; unsigned u[4]; } f;
        f.u[0] = pk2(lo[0], lo[1]);
        f.u[1] = pk2(lo[2], lo[3]);
        f.u[2] = pk2(hi[0], hi[1]);
        f.u[3] = pk2(hi[2], hi[3]);
        afrag[kt] = f.s8;
      }

      // ---- issue NEXT half's rbf loads (covered by this half's work) ----
      {
        const int nrow = (mt == 0) ? (prow + 16) : prow_nxt;
        const float* s = rbf + (size_t)(nrow + ln) * RD + q * 8;
        pre[0] = NTLOAD(s);      pre[1] = NTLOAD(s + 4);
        pre[2] = NTLOAD(s + 32); pre[3] = NTLOAD(s + 36);
      }

      // ---- GEMM1: acc = (rbf @ w1 + b1) * log2e (scales folded), K=64 ----
      floatx4 acc[8];
#pragma unroll
      for (int nt = 0; nt < 8; ++nt) acc[nt] = floatx4{0.f, 0.f, 0.f, 0.f};
#pragma unroll
      for (int kt = 0; kt < 2; ++kt)
#pragma unroll
        for (int nt = 0; nt < 8; ++nt) {
          short8 bfrag = *(const short8*)&w1f[kt * 8 + nt][lane][0];
          acc[nt] = __builtin_amdgcn_mfma_f32_16x16x32_bf16(
              afrag[kt], bfrag, acc[nt], 0, 0, 0);
        }

      // ---- H' = log2(1+2^acc) -> bf16 -> swizzled band (C-layout) ----
#pragma unroll
      for (int nt = 0; nt < 8; ++nt) {
        const int c  = nt * 16 + ln;
        const int cb = c >> 3, cl = c & 7;
        unsigned u01 = pk2(sp2(acc[nt][0] + b1v[nt]), sp2(acc[nt][1] + b1v[nt]));
        unsigned u23 = pk2(sp2(acc[nt][2] + b1v[nt]), sp2(acc[nt][3] + b1v[nt]));
        band[q * 4 + 0][(((cb ^ (q * 4 + 0)) & 15) << 3) | cl] = (short)u01;
        band[q * 4 + 1][(((cb ^ (q * 4 + 1)) & 15) << 3) | cl] = (short)(u01 >> 16);
        band[q * 4 + 2][(((cb ^ (q * 4 + 2)) & 15) << 3) | cl] = (short)u23;
        band[q * 4 + 3][(((cb ^ (q * 4 + 3)) & 15) << 3) | cl] = (short)(u23 >> 16);
      }
      LDS_FENCE();  // H writes must precede hfrag reads in program order

      // ---- H A-frags from band: row=ln, cols kt*32+q*8..+7 (b128, swizzled) ----
      short8 hfrag[4];
#pragma unroll
      for (int kt = 0; kt < 4; ++kt) {
        const int pb = ((kt * 4 + q) ^ ln) & 15;
        hfrag[kt] = *(const short8*)&band[ln][pb << 3];
      }
      LDS_FENCE();  // hfrag reads must precede W overwrite

      // ---- GEMM2: W = H' @ (ln2*w2) + b2, K=128 (reuse acc) ----
#pragma unroll
      for (int nt = 0; nt < 8; ++nt) acc[nt] = floatx4{0.f, 0.f, 0.f, 0.f};
#pragma unroll
      for (int kt = 0; kt < 4; ++kt)
#pragma unroll
        for (int nt = 0; nt < 8; ++nt) {
          short8 bfrag = *(const short8*)&w2f[kt * 8 + nt][lane][0];
          acc[nt] = __builtin_amdgcn_mfma_f32_16x16x32_bf16(
              hfrag[kt], bfrag, acc[nt], 0, 0, 0);
        }

      // ---- W (bf16) back into the same band ----
#pragma unroll
      for (int nt = 0; nt < 8; ++nt) {
        const int c  = nt * 16 + ln;
        const int cb = c >> 3, cl = c & 7;
        unsigned u01 = pk2(acc[nt][0] + b2v[nt], acc[nt][1] + b2v[nt]);
        unsigned u23 = pk2(acc[nt][2] + b2v[nt], acc[nt][3] + b2v[nt]);
        band[q * 4 + 0][(((cb ^ (q * 4 + 0)) & 15) << 3) | cl] = (short)u01;
        band[q * 4 + 1][(((cb ^ (q * 4 + 1)) & 15) << 3) | cl] = (short)(u01 >> 16);
        band[q * 4 + 2][(((cb ^ (q * 4 + 2)) & 15) << 3) | cl] = (short)u23;
        band[q * 4 + 3][(((cb ^ (q * 4 + 3)) & 15) << 3) | cl] = (short)(u23 >> 16);
      }
      LDS_FENCE();  // W writes must precede epilogue reads

      // ---- epilogue: 16 rows, coalesced 512B x-row reads; lane owns f=2*lane,+1 ----
#pragma unroll 4
      for (int r = 0; r < 16; ++r) {
        const int j = nbp[mt * 16 + r];   // wave-uniform -> s_load
        floatx2 xv = *(const floatx2*)(x + (size_t)j * FD + lane * 2);
        unsigned pw;
        __builtin_memcpy(&pw, &band[r][(((cb2 ^ r) & 15) << 3) | cl2], 4);  // may-alias read
        o0 = fmaf(xv[0], __builtin_bit_cast(float, pw << 16), o0);
        o1 = fmaf(xv[1], __builtin_bit_cast(float, pw & 0xFFFF0000u), o1);
      }
      LDS_FENCE();  // epilogue reads must precede next half's H writes
    }

    __builtin_nontemporal_store(floatx2{o0, o1}, (floatx2*)(out + (size_t)atom * FD + lane * 2));
  }
}

extern "C" void kernel_launch(void* const* d_in, const int* in_sizes, int n_in,
                              void* d_out, int out_size, void* d_ws, size_t ws_size,
                              hipStream_t stream) {
  const float* x   = (const float*)d_in[0];
  const float* rbf = (const float*)d_in[1];
  const int*   nbr = (const int*)d_in[2];
  const float* w1  = (const float*)d_in[3];
  const float* b1  = (const float*)d_in[4];
  const float* w2  = (const float*)d_in[5];
  const float* b2  = (const float*)d_in[6];
  float* out = (float*)d_out;

  // 80 KB LDS -> 2 blocks/CU. 500 blocks x 5 tiles each: exact, all co-resident.
  cfconv_kernel<<<dim3(500), dim3(512), 0, stream>>>(x, rbf, nbr, w1, b1, w2, b2, out);
}